// Round 4
// baseline (184.210 us; speedup 1.0000x reference)
//
#include <hip/hip_runtime.h>

// Skeleton forward kinematics: angles [B,16,6] f32, xyz [1,16,3] f32 -> out [B,16,3] f32.
// R7: NATURAL <=128 VGPR FOR 16 WAVES/CU. Evidence so far:
//   R3 (64us/disp): VGPR=132 (4 over the 128 occupancy cliff) -> 12 waves/CU. 17% VALU,
//       19% HBM, occ 10%: latency-bound, nothing busy.
//   R4/R6: store-coalescing null (16x fewer store line-touches, time unchanged) ->
//       VMEM request rate is NOT the bottleneck; don't bother coalescing loads either.
//   R5: __launch_bounds__ forcing -> VGPR=64 + catastrophic scratch spill. NEVER force.
//       But it proved 2.7 TB/s sustained at 35% occupancy -> fill concurrency scales
//       with resident waves.
// Model: per-CU outstanding line-fills (resident waves x in-flight loads) x ~600-900cy
// latency bounds throughput. Grid caps at 16 waves/CU; VGPR 132 caps at 12. Fix: split
// prefetch 15+9 float4 at joint boundaries (joints 0..9 | 10..15), issue batch-2 after
// edge 3 when af[0..24) is dead. Peak live ~124 VGPR -> 4 waves/SIMD. Batch-2 latency
// hides under edges 4..9. Stores: immediate scalar (R3-proven; LDS staging was neutral).

namespace {

constexpr int NJ = 16;

__device__ __forceinline__ void rot6d(const float* __restrict__ a, float R[9]) {
    float inv1 = rsqrtf(a[0]*a[0] + a[1]*a[1] + a[2]*a[2]);
    float b10 = a[0]*inv1, b11 = a[1]*inv1, b12 = a[2]*inv1;
    float d = b10*a[3] + b11*a[4] + b12*a[5];
    float c0 = a[3] - d*b10, c1 = a[4] - d*b11, c2 = a[5] - d*b12;
    float inv2 = rsqrtf(c0*c0 + c1*c1 + c2*c2);
    float b20 = c0*inv2, b21 = c1*inv2, b22 = c2*inv2;
    R[0] = b10; R[1] = b11; R[2] = b12;
    R[3] = b20; R[4] = b21; R[5] = b22;
    R[6] = b11*b22 - b12*b21;
    R[7] = b12*b20 - b10*b22;
    R[8] = b10*b21 - b11*b20;
}

// One tree edge: c = child joint, p = parent joint, APTR = angles for joint c.
// Identical math to R3 (proven codegen); macro so both af/af2 regions get the
// same inlined body with compile-time indices.
#define EDGE(c, p, APTR)                                                        \
    {                                                                           \
        if ((p) == 3) {                                                         \
            _Pragma("unroll")                                                   \
            for (int k = 0; k < 9; ++k) Rw[k] = Rw3[k];                         \
            pw[0] = pw3[0]; pw[1] = pw3[1]; pw[2] = pw3[2];                     \
        }                                                                       \
        float R[9];                                                             \
        rot6d((APTR), R);                                                       \
        float tx = xyz[(c) * 3 + 0] - xyz[(p) * 3 + 0];                         \
        float ty = xyz[(c) * 3 + 1] - xyz[(p) * 3 + 1];                         \
        float tz = xyz[(c) * 3 + 2] - xyz[(p) * 3 + 2];                         \
        float lt0 = R[0]*tx + R[1]*ty + R[2]*tz;                                \
        float lt1 = R[3]*tx + R[4]*ty + R[5]*tz;                                \
        float lt2 = R[6]*tx + R[7]*ty + R[8]*tz;                                \
        float np0 = Rw[0]*lt0 + Rw[1]*lt1 + Rw[2]*lt2 + pw[0];                  \
        float np1 = Rw[3]*lt0 + Rw[4]*lt1 + Rw[5]*lt2 + pw[1];                  \
        float np2 = Rw[6]*lt0 + Rw[7]*lt1 + Rw[8]*lt2 + pw[2];                  \
        float T[9];                                                             \
        _Pragma("unroll")                                                       \
        for (int i = 0; i < 3; ++i)                                             \
            _Pragma("unroll")                                                   \
            for (int j = 0; j < 3; ++j)                                         \
                T[i*3 + j] = Rw[i*3 + 0]*R[0*3 + j]                             \
                           + Rw[i*3 + 1]*R[1*3 + j]                             \
                           + Rw[i*3 + 2]*R[2*3 + j];                            \
        _Pragma("unroll")                                                       \
        for (int k = 0; k < 9; ++k) Rw[k] = T[k];                               \
        pw[0] = np0; pw[1] = np1; pw[2] = np2;                                  \
        ob[(c)*3 + 0] = np0; ob[(c)*3 + 1] = np1; ob[(c)*3 + 2] = np2;          \
        if ((c) == 3) {                                                         \
            _Pragma("unroll")                                                   \
            for (int k = 0; k < 9; ++k) Rw3[k] = Rw[k];                         \
            pw3[0] = pw[0]; pw3[1] = pw[1]; pw3[2] = pw[2];                     \
        }                                                                       \
    }

__global__ __launch_bounds__(256) void skel_kernel(
    const float* __restrict__ angles,
    const float* __restrict__ xyz,
    float* __restrict__ out,
    int batch)
{
    const int b = blockIdx.x * 256 + threadIdx.x;
    if (b >= batch) return;

    const float4* a4 = (const float4*)(angles + (size_t)b * (NJ * 6));
    float* ob = out + (size_t)b * (NJ * 3);

    // ---- batch-1 prefetch: joints 0..9 (15 float4 = floats [0,60)) ----
    float4 v[15];
#pragma unroll
    for (int k = 0; k < 15; ++k) v[k] = a4[k];
    __builtin_amdgcn_sched_barrier(0);   // loads may not sink into the chain

    float af[60];
#pragma unroll
    for (int k = 0; k < 15; ++k) {
        af[4*k + 0] = v[k].x; af[4*k + 1] = v[k].y;
        af[4*k + 2] = v[k].z; af[4*k + 3] = v[k].w;
    }

    float Rw[9], pw[3], Rw3[9], pw3[3];

    // ---- joint 0 ----
    rot6d(&af[0], Rw);
    {
        float x = xyz[0], y = xyz[1], z = xyz[2];
        pw[0] = Rw[0]*x + Rw[1]*y + Rw[2]*z;
        pw[1] = Rw[3]*x + Rw[4]*y + Rw[5]*z;
        pw[2] = Rw[6]*x + Rw[7]*y + Rw[8]*z;
    }
    ob[0] = pw[0]; ob[1] = pw[1]; ob[2] = pw[2];

    // edges c=1..3 (chain 0-1-2-3); af[0..24) dead afterwards
    EDGE(1, 0, &af[6]);
    EDGE(2, 1, &af[12]);
    EDGE(3, 2, &af[18]);

    // ---- batch-2 prefetch: joints 10..15 (9 float4 = floats [60,96)) ----
    // Issued here so ~900cy latency hides under edges 4..9 (~1000cy compute).
    float4 w[9];
#pragma unroll
    for (int k = 0; k < 9; ++k) w[k] = a4[15 + k];
    __builtin_amdgcn_sched_barrier(0);   // keep issue point here, don't sink

    // edges c=4..9 (branch 3-4-5, then 3-6-7-8-9); consumes af[24..60)
    EDGE(4, 3, &af[24]);
    EDGE(5, 4, &af[30]);
    EDGE(6, 3, &af[36]);
    EDGE(7, 6, &af[42]);
    EDGE(8, 7, &af[48]);
    EDGE(9, 8, &af[54]);

    // repack batch-2 (compiler inserts the vmcnt wait here, after the hide window)
    float af2[36];
#pragma unroll
    for (int k = 0; k < 9; ++k) {
        af2[4*k + 0] = w[k].x; af2[4*k + 1] = w[k].y;
        af2[4*k + 2] = w[k].z; af2[4*k + 3] = w[k].w;
    }

    // edges c=10..15 (finish chain 6..10; branch 3-11-12-13-14-15)
    EDGE(10,  9, &af2[0]);
    EDGE(11,  3, &af2[6]);
    EDGE(12, 11, &af2[12]);
    EDGE(13, 12, &af2[18]);
    EDGE(14, 13, &af2[24]);
    EDGE(15, 14, &af2[30]);
}

#undef EDGE

} // namespace

extern "C" void kernel_launch(void* const* d_in, const int* in_sizes, int n_in,
                              void* d_out, int out_size, void* d_ws, size_t ws_size,
                              hipStream_t stream) {
    const float* angles = (const float*)d_in[0];   // [B, 16, 6] f32
    const float* xyz    = (const float*)d_in[1];   // [1, 16, 3] f32
    float* out          = (float*)d_out;           // [B, 16, 3] f32

    const int batch = in_sizes[0] / (NJ * 6);
    dim3 grid((batch + 255) / 256);
    skel_kernel<<<grid, 256, 0, stream>>>(angles, xyz, out, batch);
}